// Round 8
// baseline (3063.715 us; speedup 1.0000x reference)
//
#include <hip/hip_runtime.h>
#include <hip/hip_bf16.h>
#include <stdint.h>

#define B_    64
#define T_    512
#define H_    512
#define G_    2048    // 4*H
#define TAGS_ 20

typedef __hip_bfloat16 bf16;
typedef __bf16 bf16x8 __attribute__((ext_vector_type(8)));
typedef float  f32x4  __attribute__((ext_vector_type(4)));

__device__ __forceinline__ float sigmoidf_(float x) { return 1.0f / (1.0f + __expf(-x)); }
__device__ __forceinline__ float tanhf_(float x)    { return 1.0f - 2.0f / (__expf(2.0f * x) + 1.0f); }

// ---------------- prep kernels ----------------

__global__ void k_zero(uint32_t* __restrict__ p, int n) {
    for (int i = blockIdx.x * blockDim.x + threadIdx.x; i < n; i += gridDim.x * blockDim.x)
        p[i] = 0u;
}

__global__ void k_addb(const float* __restrict__ a, const float* __restrict__ b,
                       float* __restrict__ o, int n) {
    for (int i = blockIdx.x * blockDim.x + threadIdx.x; i < n; i += gridDim.x * blockDim.x)
        o[i] = a[i] + b[i];
}

__global__ __launch_bounds__(256) void k_lens(const int* __restrict__ x, int* __restrict__ lens) {
    int b = blockIdx.x;
    int cnt = 0;
    for (int tpos = threadIdx.x; tpos < T_; tpos += 256)
        cnt += (x[(size_t)b * T_ + tpos] == 0) ? 1 : 0;
    #pragma unroll
    for (int off = 32; off; off >>= 1) cnt += __shfl_xor(cnt, off);
    __shared__ int tot;
    if (threadIdx.x == 0) tot = 0;
    __syncthreads();
    if ((threadIdx.x & 63) == 0) atomicAdd(&tot, cnt);
    __syncthreads();
    if (threadIdx.x == 0) lens[b] = T_ - tot;
}

// E[t][b][d] = bf16(emb[x[b][t]][d])
__global__ void k_gather(const int* __restrict__ x, const float* __restrict__ emb,
                         bf16* __restrict__ E) {
    int t = blockIdx.x, b = blockIdx.y;
    int tok = x[(size_t)b * T_ + t];
    const float* src = emb + (size_t)tok * H_;
    bf16* dst = E + ((size_t)t * B_ + b) * H_;
    for (int d = threadIdx.x; d < H_; d += blockDim.x)
        dst[d] = __float2bfloat16(src[d]);
}

// Pack weights into fragment-linear order (fused fp32->bf16)
__global__ __launch_bounds__(256) void k_pack(const float* __restrict__ Wih0, const float* __restrict__ Whh0,
                                              const float* __restrict__ Wih1, const float* __restrict__ Whh1,
                                              bf16* __restrict__ Wp) {
    const int s = blockIdx.x, q = blockIdx.y, l = blockIdx.z;
    const float* Wx = l ? Wih1 : Wih0;
    const float* Wh = l ? Whh1 : Whh0;
    bf16* base = Wp + (size_t)(l * 32 + s) * 65536;
    for (int u = threadIdx.x; u < 2048; u += 256) {
        int kc = u >> 6, lane = u & 63;
        int row = q * H_ + s * 16 + (lane & 15);
        int col = (kc & 15) * 32 + (lane >> 4) * 8;
        const float* src = ((kc < 16) ? Wx : Wh) + (size_t)row * H_ + col;
        bf16* dst = base + ((size_t)(q * 32 + kc) * 64 + lane) * 8;
        #pragma unroll
        for (int e = 0; e < 8; ++e) dst[e] = __float2bfloat16(src[e]);
    }
}

// ---------------- sync helpers ----------------
// ONE wave per block polls; ONE coalesced 128B load per iteration covers both
// dependency arrays (lane<32 -> fa[lane] >= ta ; lane>=32 -> fb[lane-32] >= tb).
// Publishers use plain sc1 dword stores (no RMW). No cache-wide fences anywhere.

__device__ __forceinline__ void wave0_poll2(const int* fa, int ta,
                                            const int* fb, int tb, int lane) {
    const int* p = (lane < 32) ? (fa + lane) : (fb + (lane - 32));
    const int thr = (lane < 32) ? ta : tb;
    int gd = 0;
    while (true) {
        int v;
        asm volatile("global_load_dword %0, %1, off sc0 sc1\n\ts_waitcnt vmcnt(0)"
                     : "=v"(v) : "v"(p) : "memory");
        if (__all(v >= thr)) break;
        if (++gd > (1 << 18)) break;            // bounded worst case
        __builtin_amdgcn_s_sleep(2);            // ~128cy backoff
    }
    __builtin_amdgcn_sched_barrier(0);
}

#define ISSUE16(arr, base, SC)                                               \
    _Pragma("unroll")                                                        \
    for (int kc = 0; kc < 16; ++kc) {                                        \
        asm volatile("global_load_dwordx4 %0, %1, off" SC                    \
                     : "=v"(arr[kc]) : "v"((base) + kc * 32));               \
    }

#define WAITALL()                                                            \
    asm volatile("s_waitcnt vmcnt(0)" ::: "memory");                         \
    __builtin_amdgcn_sched_barrier(0);

#define MFMA16(arr, woff)                                                    \
    _Pragma("unroll")                                                        \
    for (int kc = 0; kc < 16; ++kc) {                                        \
        f32x4 wf = wldsv[(size_t)(q * 32 + (woff) + kc) * 64 + lane];        \
        acc[kc & 3] = __builtin_amdgcn_mfma_f32_16x16x32_bf16(               \
            __builtin_bit_cast(bf16x8, arr[kc]),                             \
            __builtin_bit_cast(bf16x8, wf), acc[kc & 3], 0, 0, 0);           \
    }

// ---------------- persistent 2-layer LSTM ----------------
// 256 blocks (1/CU, 133KB dyn LDS). block = (g=bid&7 -> (layer,m), strip s=bid>>3).
// Weights in LDS (fragment-linear). c in registers. Cross-block data via sc0 sc1
// (L3-coherent). Sync: per-strip flag stores + single-wave coalesced polling.
__global__ __launch_bounds__(256, 1) void k_lstm(
    const bf16* __restrict__ Wp, const bf16* __restrict__ E,
    const float* __restrict__ bias0, const float* __restrict__ bias1,
    bf16* __restrict__ h0ring, bf16* __restrict__ h1ring,
    int* __restrict__ fx, float* __restrict__ last1, const int* __restrict__ lens)
{
    extern __shared__ char smem[];                       // [0,128K) weights, [128K,+5K) gates
    f32x4* wldsv = (f32x4*)smem;
    float (*glds)[16][20] = (float (*)[16][20])(smem + 131072);

    const int bid   = blockIdx.x;
    const int g     = bid & 7;           // group: layer*4+m
    const int s     = bid >> 3;          // strip 0..31
    const int layer = g >> 2;
    const int m     = g & 3;
    const int tid   = threadIdx.x;
    const int lane  = tid & 63;
    const int q     = tid >> 6;          // wave = gate
    const int kq    = (lane >> 4) * 8;
    const int arow  = m * 16 + (lane & 15);

    // ---- stage this block's 128KB weight slice into LDS ----
    {
        const f32x4* wsrc = (const f32x4*)(Wp + (size_t)(layer * 32 + s) * 65536);
        for (int i = tid; i < 8192; i += 256) wldsv[i] = wsrc[i];
    }

    // ---- elementwise mapping: one (b,j) per thread, c in register ----
    const int eb   = tid >> 4;
    const int ej   = tid & 15;
    const int brow = m * 16 + eb;
    const int jcol = s * 16 + ej;
    float c_reg = 0.f;
    const float* bias = layer ? bias1 : bias0;
    const float bi0 = bias[0 * H_ + jcol];
    const float bi1 = bias[1 * H_ + jcol];
    const float bi2 = bias[2 * H_ + jcol];
    const float bi3 = bias[3 * H_ + jcol];
    int target = lens[brow] - 1;
    if (target < 0) target = T_ - 1;

    int*       fown = fx + g * 32;             // own group's 32 per-strip flags (128B line)
    const int* foth = fx + (g ^ 4) * 32;       // other layer, same m

    bf16* myring = layer ? h1ring : h0ring;
    const int rb = (lane >> 4) * 4;
    const int l15 = lane & 15;

    __syncthreads();                           // weights staged

    for (int tt = 0; tt < T_; ++tt) {
        f32x4 acc[4];
        #pragma unroll
        for (int i = 0; i < 4; ++i) acc[i] = f32x4{0.f, 0.f, 0.f, 0.f};
        f32x4 ax[16], ah[16];
        const size_t slot_w = (size_t)(tt & 7) * (B_ * H_);
        const size_t slot_r = (size_t)((tt - 1) & 7) * (B_ * H_);

        if (layer == 0) {
            // x-part from E: zero dependencies — before the sync
            const bf16* xp = E + ((size_t)tt * B_ + arow) * H_ + kq;
            ISSUE16(ax, xp, "")
            WAITALL()
            MFMA16(ax, 0)
            // wave0: own group done tt-1 AND l1 consumed ring slot (lag 8)
            if (q == 0) wave0_poll2(fown, tt, foth, (tt >= 8) ? (tt - 7) : 0, lane);
            __syncthreads();
            const bf16* hp = h0ring + slot_r + (size_t)arow * H_ + kq;
            ISSUE16(ah, hp, " sc0 sc1")
            WAITALL()
            MFMA16(ah, 16)
        } else {
            // wave0: own group done tt-1 AND l0 done step tt — one merged poll
            if (q == 0) wave0_poll2(fown, tt, foth, tt + 1, lane);
            __syncthreads();
            const bf16* hp = h1ring + slot_r + (size_t)arow * H_ + kq;
            const bf16* xp = h0ring + slot_w + (size_t)arow * H_ + kq;
            ISSUE16(ah, hp, " sc0 sc1")
            ISSUE16(ax, xp, " sc0 sc1")
            WAITALL()                                          // both data RTs overlap
            MFMA16(ax, 0)
            MFMA16(ah, 16)
        }

        f32x4 gsum = (acc[0] + acc[1]) + (acc[2] + acc[3]);

        // ---- gate exchange via LDS ----
        *reinterpret_cast<f32x4*>(&glds[q][l15][rb]) = gsum;
        __syncthreads();

        // ---- elementwise LSTM update ----
        float gi = sigmoidf_(glds[0][ej][eb] + bi0);
        float gf = sigmoidf_(glds[1][ej][eb] + bi1);
        float gg = tanhf_  (glds[2][ej][eb] + bi2);
        float go = sigmoidf_(glds[3][ej][eb] + bi3);
        c_reg = gf * c_reg + gi * gg;
        float hn = go * tanhf_(c_reg);

        {
            bf16 hb = __float2bfloat16(hn);
            uint32_t hv = (uint32_t)__builtin_bit_cast(unsigned short, hb);
            bf16* hw = myring + slot_w + (size_t)brow * H_ + jcol;
            asm volatile("global_store_short %0, %1, off sc0 sc1" :: "v"(hw), "v"(hv) : "memory");
        }
        if (layer == 1 && tt == target)
            last1[(size_t)brow * H_ + jcol] = hn;

        asm volatile("s_waitcnt vmcnt(0)" ::: "memory");   // per-wave stores at L3
        __syncthreads();                                   // whole block drained
        if (tid == 0) {                                    // publish: one plain store
            int fv = tt + 1;
            int* fp = fown + s;
            asm volatile("global_store_dword %0, %1, off sc0 sc1" :: "v"(fp), "v"(fv) : "memory");
        }
    }
}

// out[b][tag] = last1[b] . Wout[tag] + bout[tag]   (fp32)
__global__ __launch_bounds__(64) void k_out(const float* __restrict__ last1,
                                            const float* __restrict__ Wout,
                                            const float* __restrict__ bout,
                                            float* __restrict__ out) {
    int b = blockIdx.x, tg = blockIdx.y, lane = threadIdx.x;
    float sum = 0.f;
    for (int d = lane; d < H_; d += 64)
        sum += last1[(size_t)b * H_ + d] * Wout[(size_t)tg * H_ + d];
    #pragma unroll
    for (int off = 32; off; off >>= 1) sum += __shfl_xor(sum, off);
    if (lane == 0) out[b * TAGS_ + tg] = sum + bout[tg];
}

// ---------------- host ----------------

extern "C" void kernel_launch(void* const* d_in, const int* in_sizes, int n_in,
                              void* d_out, int out_size, void* d_ws, size_t ws_size,
                              hipStream_t stream)
{
    const int*   x    = (const int*)  d_in[0];
    const float* emb  = (const float*)d_in[1];
    const float* Wih0 = (const float*)d_in[2];
    const float* Whh0 = (const float*)d_in[3];
    const float* bih0 = (const float*)d_in[4];
    const float* bhh0 = (const float*)d_in[5];
    const float* Wih1 = (const float*)d_in[6];
    const float* Whh1 = (const float*)d_in[7];
    const float* bih1 = (const float*)d_in[8];
    const float* bhh1 = (const float*)d_in[9];
    const float* Wout = (const float*)d_in[10];
    const float* bout = (const float*)d_in[11];
    float* out = (float*)d_out;

    char* p = (char*)d_ws;
    bf16* E    = (bf16*)p;  p += (size_t)T_ * B_ * H_ * 2;      // 32 MB
    bf16* Wp   = (bf16*)p;  p += (size_t)2 * 32 * 65536 * 2;    // 8 MB packed weights
    float* bias0 = (float*)p; p += (size_t)G_ * 4;
    float* bias1 = (float*)p; p += (size_t)G_ * 4;
    char* zbase = p;                                            // zeroed every launch
    bf16* h0ring = (bf16*)p; p += (size_t)8 * B_ * H_ * 2;      // 512 KB
    bf16* h1ring = (bf16*)p; p += (size_t)8 * B_ * H_ * 2;      // 512 KB
    int*  fx     = (int*)p;  p += 8 * 32 * 4;                   // per-strip progress flags
    size_t zbytes = (size_t)(p - zbase);
    float* last1 = (float*)p; p += (size_t)B_ * H_ * 4;
    int* lens = (int*)p; p += 256;

    (void)hipFuncSetAttribute((const void*)k_lstm,
                              hipFuncAttributeMaxDynamicSharedMemorySize, 136192);

    k_zero<<<dim3(128), dim3(256), 0, stream>>>((uint32_t*)zbase, (int)(zbytes / 4));
    k_lens<<<dim3(B_), dim3(256), 0, stream>>>(x, lens);
    k_addb<<<dim3(8), dim3(256), 0, stream>>>(bih0, bhh0, bias0, G_);
    k_addb<<<dim3(8), dim3(256), 0, stream>>>(bih1, bhh1, bias1, G_);
    k_pack<<<dim3(32, 4, 2), dim3(256), 0, stream>>>(Wih0, Whh0, Wih1, Whh1, Wp);
    k_gather<<<dim3(T_, B_), dim3(256), 0, stream>>>(x, emb, E);

    k_lstm<<<dim3(256), dim3(256), 136192, stream>>>(Wp, E, bias0, bias1,
                                                     h0ring, h1ring, fx, last1, lens);

    k_out<<<dim3(B_, TAGS_), dim3(64), 0, stream>>>(last1, Wout, bout, out);
}

// Round 9
// 2378.450 us; speedup vs baseline: 1.2881x; 1.2881x over previous
//
#include <hip/hip_runtime.h>
#include <hip/hip_bf16.h>
#include <stdint.h>

#define B_    64
#define T_    512
#define H_    512
#define G_    2048    // 4*H
#define TAGS_ 20

typedef __hip_bfloat16 bf16;
typedef __bf16 bf16x8 __attribute__((ext_vector_type(8)));
typedef float  f32x4  __attribute__((ext_vector_type(4)));

__device__ __forceinline__ float sigmoidf_(float x) { return 1.0f / (1.0f + __expf(-x)); }
__device__ __forceinline__ float tanhf_(float x)    { return 1.0f - 2.0f / (__expf(2.0f * x) + 1.0f); }

// ---------------- prep kernels ----------------

__global__ void k_zero(uint32_t* __restrict__ p, int n) {
    for (int i = blockIdx.x * blockDim.x + threadIdx.x; i < n; i += gridDim.x * blockDim.x)
        p[i] = 0u;
}

__global__ void k_addb(const float* __restrict__ a, const float* __restrict__ b,
                       float* __restrict__ o, int n) {
    for (int i = blockIdx.x * blockDim.x + threadIdx.x; i < n; i += gridDim.x * blockDim.x)
        o[i] = a[i] + b[i];
}

__global__ __launch_bounds__(256) void k_lens(const int* __restrict__ x, int* __restrict__ lens) {
    int b = blockIdx.x;
    int cnt = 0;
    for (int tpos = threadIdx.x; tpos < T_; tpos += 256)
        cnt += (x[(size_t)b * T_ + tpos] == 0) ? 1 : 0;
    #pragma unroll
    for (int off = 32; off; off >>= 1) cnt += __shfl_xor(cnt, off);
    __shared__ int tot;
    if (threadIdx.x == 0) tot = 0;
    __syncthreads();
    if ((threadIdx.x & 63) == 0) atomicAdd(&tot, cnt);
    __syncthreads();
    if (threadIdx.x == 0) lens[b] = T_ - tot;
}

// E[t][b][d] = bf16(emb[x[b][t]][d])
__global__ void k_gather(const int* __restrict__ x, const float* __restrict__ emb,
                         bf16* __restrict__ E) {
    int t = blockIdx.x, b = blockIdx.y;
    int tok = x[(size_t)b * T_ + t];
    const float* src = emb + (size_t)tok * H_;
    bf16* dst = E + ((size_t)t * B_ + b) * H_;
    for (int d = threadIdx.x; d < H_; d += blockDim.x)
        dst[d] = __float2bfloat16(src[d]);
}

// Pack weights into fragment-linear order (fused fp32->bf16)
__global__ __launch_bounds__(256) void k_pack(const float* __restrict__ Wih0, const float* __restrict__ Whh0,
                                              const float* __restrict__ Wih1, const float* __restrict__ Whh1,
                                              bf16* __restrict__ Wp) {
    const int s = blockIdx.x, q = blockIdx.y, l = blockIdx.z;
    const float* Wx = l ? Wih1 : Wih0;
    const float* Wh = l ? Whh1 : Whh0;
    bf16* base = Wp + (size_t)(l * 32 + s) * 65536;
    for (int u = threadIdx.x; u < 2048; u += 256) {
        int kc = u >> 6, lane = u & 63;
        int row = q * H_ + s * 16 + (lane & 15);
        int col = (kc & 15) * 32 + (lane >> 4) * 8;
        const float* src = ((kc < 16) ? Wx : Wh) + (size_t)row * H_ + col;
        bf16* dst = base + ((size_t)(q * 32 + kc) * 64 + lane) * 8;
        #pragma unroll
        for (int e = 0; e < 8; ++e) dst[e] = __float2bfloat16(src[e]);
    }
}

// ---------------- sync helpers ----------------
// Single wave polls; one coalesced load covers both flag arrays.
// Spin-first then backoff: low observe lag in the steady pipeline.

__device__ __forceinline__ void wave0_poll2(const int* fa, int ta,
                                            const int* fb, int tb, int lane) {
    const int* p = (lane < 32) ? (fa + lane) : (fb + (lane - 32));
    const int thr = (lane < 32) ? ta : tb;
    int gd = 0;
    while (true) {
        int v;
        asm volatile("global_load_dword %0, %1, off sc0 sc1\n\ts_waitcnt vmcnt(0)"
                     : "=v"(v) : "v"(p) : "memory");
        if (__all(v >= thr)) break;
        if (++gd > (1 << 18)) break;            // bounded worst case
        if (gd > 16) __builtin_amdgcn_s_sleep(2);
    }
    __builtin_amdgcn_sched_barrier(0);
}

#define ISSUE16(arr, base, SC)                                               \
    _Pragma("unroll")                                                        \
    for (int kc = 0; kc < 16; ++kc) {                                        \
        asm volatile("global_load_dwordx4 %0, %1, off" SC                    \
                     : "=v"(arr[kc]) : "v"((base) + kc * 32));               \
    }

#define WAITALL()                                                            \
    asm volatile("s_waitcnt vmcnt(0)" ::: "memory");                         \
    __builtin_amdgcn_sched_barrier(0);

// A from registers (l0 x-part from cached E)
#define MFMA16_REG(arr, woff)                                                \
    _Pragma("unroll")                                                        \
    for (int kc = 0; kc < 16; ++kc) {                                        \
        f32x4 wf = wldsv[(size_t)(q * 32 + (woff) + kc) * 64 + lane];        \
        acc[kc & 3] = __builtin_amdgcn_mfma_f32_16x16x32_bf16(               \
            __builtin_bit_cast(bf16x8, arr[kc]),                             \
            __builtin_bit_cast(bf16x8, wf), acc[kc & 3], 0, 0, 0);           \
    }

// A from the LDS stage buffer (fragment-linear, conflict-free)
#define MFMA16_LDS(woff)                                                     \
    _Pragma("unroll")                                                        \
    for (int kc = 0; kc < 16; ++kc) {                                        \
        f32x4 af = stagev[kc * 64 + lane];                                   \
        f32x4 wf = wldsv[(size_t)(q * 32 + (woff) + kc) * 64 + lane];        \
        acc[kc & 3] = __builtin_amdgcn_mfma_f32_16x16x32_bf16(               \
            __builtin_bit_cast(bf16x8, af),                                  \
            __builtin_bit_cast(bf16x8, wf), acc[kc & 3], 0, 0, 0);           \
    }

// ---------------- persistent 2-layer LSTM ----------------
// 256 blocks (1/CU, 144KB dyn LDS). block = (g=bid&7 -> (layer,m), strip s=bid>>3).
// Weights in LDS. A-fragments STAGED in LDS once per block (kills the 4x per-wave
// sc-load replication that dominated rounds 3-8). Packed 16B h-stores (kills the
// 256x 2B scattered store drain). Sync: per-strip flags + single-wave poll.
__global__ __launch_bounds__(256, 1) void k_lstm(
    const bf16* __restrict__ Wp, const bf16* __restrict__ E,
    const float* __restrict__ bias0, const float* __restrict__ bias1,
    bf16* __restrict__ h0ring, bf16* __restrict__ h1ring,
    int* __restrict__ fx, float* __restrict__ last1, const int* __restrict__ lens)
{
    extern __shared__ char smem[];                 // [0,128K) weights | [128K,144K) stage
    f32x4* wldsv  = (f32x4*)smem;
    f32x4* stagev = (f32x4*)(smem + 131072);       // 16KB A-fragment stage
    float (*glds)[16][20] = (float (*)[16][20])(smem + 131072);        // alias (post-MFMA)
    bf16* hlds = (bf16*)(smem + 131072 + 5120);                        // alias (+5KB)

    const int bid   = blockIdx.x;
    const int g     = bid & 7;           // group: layer*4+m
    const int s     = bid >> 3;          // strip 0..31
    const int layer = g >> 2;
    const int m     = g & 3;
    const int tid   = threadIdx.x;
    const int lane  = tid & 63;
    const int q     = tid >> 6;          // wave = gate
    const int kq    = (lane >> 4) * 8;
    const int arow  = m * 16 + (lane & 15);

    // ---- stage this block's 128KB weight slice into LDS ----
    {
        const f32x4* wsrc = (const f32x4*)(Wp + (size_t)(layer * 32 + s) * 65536);
        for (int i = tid; i < 8192; i += 256) wldsv[i] = wsrc[i];
    }

    // ---- elementwise mapping: one (b,j) per thread, c in register ----
    const int eb   = tid >> 4;
    const int ej   = tid & 15;
    const int brow = m * 16 + eb;
    const int jcol = s * 16 + ej;
    float c_reg = 0.f;
    const float* bias = layer ? bias1 : bias0;
    const float bi0 = bias[0 * H_ + jcol];
    const float bi1 = bias[1 * H_ + jcol];
    const float bi2 = bias[2 * H_ + jcol];
    const float bi3 = bias[3 * H_ + jcol];
    int target = lens[brow] - 1;
    if (target < 0) target = T_ - 1;

    int*       fown = fx + g * 32;             // own group's 32 per-strip flags
    const int* foth = fx + (g ^ 4) * 32;       // other layer, same m

    bf16* myring = layer ? h1ring : h0ring;
    const int rb = (lane >> 4) * 4;
    const int l15 = lane & 15;

    __syncthreads();                           // weights staged

    for (int tt = 0; tt < T_; ++tt) {
        f32x4 acc[4];
        #pragma unroll
        for (int i = 0; i < 4; ++i) acc[i] = f32x4{0.f, 0.f, 0.f, 0.f};
        const size_t slot_w = (size_t)(tt & 7) * (B_ * H_);
        const size_t slot_r = (size_t)((tt - 1) & 7) * (B_ * H_);

        if (layer == 0) {
            // x-part from E (cacheable, off the sync chain), into registers
            f32x4 ax[16];
            const bf16* xp = E + ((size_t)tt * B_ + arow) * H_ + kq;
            ISSUE16(ax, xp, "")
            WAITALL()
            MFMA16_REG(ax, 0)
            // own group done tt-1 AND l1 consumed ring slot (lag 8)
            if (q == 0) wave0_poll2(fown, tt, foth, (tt >= 8) ? (tt - 7) : 0, lane);
            __syncthreads();
            // stage h: 4 fragments per wave, fragment-linear
            f32x4 hreg[4];
            const bf16* hp = h0ring + slot_r + (size_t)arow * H_ + kq;
            #pragma unroll
            for (int i = 0; i < 4; ++i)
                asm volatile("global_load_dwordx4 %0, %1, off sc0 sc1"
                             : "=v"(hreg[i]) : "v"(hp + (q * 4 + i) * 32));
            WAITALL()
            #pragma unroll
            for (int i = 0; i < 4; ++i) stagev[(q * 4 + i) * 64 + lane] = hreg[i];
            __syncthreads();
            MFMA16_LDS(16)
        } else {
            // own group done tt-1 AND l0 done step tt — one merged poll
            if (q == 0) wave0_poll2(fown, tt, foth, tt + 1, lane);
            __syncthreads();
            // issue x then h loads; stage x while h is in flight
            f32x4 xreg[4], hreg[4];
            const bf16* xp = h0ring + slot_w + (size_t)arow * H_ + kq;
            const bf16* hp = h1ring + slot_r + (size_t)arow * H_ + kq;
            #pragma unroll
            for (int i = 0; i < 4; ++i)
                asm volatile("global_load_dwordx4 %0, %1, off sc0 sc1"
                             : "=v"(xreg[i]) : "v"(xp + (q * 4 + i) * 32));
            #pragma unroll
            for (int i = 0; i < 4; ++i)
                asm volatile("global_load_dwordx4 %0, %1, off sc0 sc1"
                             : "=v"(hreg[i]) : "v"(hp + (q * 4 + i) * 32));
            asm volatile("s_waitcnt vmcnt(4)" ::: "memory");   // x arrived
            __builtin_amdgcn_sched_barrier(0);
            #pragma unroll
            for (int i = 0; i < 4; ++i) stagev[(q * 4 + i) * 64 + lane] = xreg[i];
            __syncthreads();
            MFMA16_LDS(0)                       // h RT hides under x-MFMAs
            __syncthreads();                    // stage reads done before overwrite
            WAITALL()                           // h arrived (mostly elapsed)
            #pragma unroll
            for (int i = 0; i < 4; ++i) stagev[(q * 4 + i) * 64 + lane] = hreg[i];
            __syncthreads();
            MFMA16_LDS(16)
        }

        f32x4 gsum = (acc[0] + acc[1]) + (acc[2] + acc[3]);

        // ---- gate exchange via LDS (aliases the stage buffer) ----
        __syncthreads();                        // all stage reads complete
        *reinterpret_cast<f32x4*>(&glds[q][l15][rb]) = gsum;
        __syncthreads();

        // ---- elementwise LSTM update ----
        float gi = sigmoidf_(glds[0][ej][eb] + bi0);
        float gf = sigmoidf_(glds[1][ej][eb] + bi1);
        float gg = tanhf_  (glds[2][ej][eb] + bi2);
        float go = sigmoidf_(glds[3][ej][eb] + bi3);
        c_reg = gf * c_reg + gi * gg;
        float hn = go * tanhf_(c_reg);

        hlds[eb * 16 + ej] = __float2bfloat16(hn);
        if (layer == 1 && tt == target)
            last1[(size_t)brow * H_ + jcol] = hn;
        __syncthreads();

        // ---- packed h store: 32 x 16B transactions (wave0) ----
        if (tid < 32) {
            int r = tid >> 1, half = tid & 1;
            f32x4 v = *reinterpret_cast<f32x4*>(&hlds[r * 16 + half * 8]);
            bf16* dst = myring + slot_w + (size_t)(m * 16 + r) * H_ + s * 16 + half * 8;
            asm volatile("global_store_dwordx4 %0, %1, off sc0 sc1" :: "v"(dst), "v"(v) : "memory");
        }
        asm volatile("s_waitcnt vmcnt(0)" ::: "memory");   // ring data at L3
        __syncthreads();
        if (tid == 0) {                                    // publish
            int fv = tt + 1;
            int* fp = fown + s;
            asm volatile("global_store_dword %0, %1, off sc0 sc1" :: "v"(fp), "v"(fv) : "memory");
        }
    }
}

// out[b][tag] = last1[b] . Wout[tag] + bout[tag]   (fp32)
__global__ __launch_bounds__(64) void k_out(const float* __restrict__ last1,
                                            const float* __restrict__ Wout,
                                            const float* __restrict__ bout,
                                            float* __restrict__ out) {
    int b = blockIdx.x, tg = blockIdx.y, lane = threadIdx.x;
    float sum = 0.f;
    for (int d = lane; d < H_; d += 64)
        sum += last1[(size_t)b * H_ + d] * Wout[(size_t)tg * H_ + d];
    #pragma unroll
    for (int off = 32; off; off >>= 1) sum += __shfl_xor(sum, off);
    if (lane == 0) out[b * TAGS_ + tg] = sum + bout[tg];
}

// ---------------- host ----------------

extern "C" void kernel_launch(void* const* d_in, const int* in_sizes, int n_in,
                              void* d_out, int out_size, void* d_ws, size_t ws_size,
                              hipStream_t stream)
{
    const int*   x    = (const int*)  d_in[0];
    const float* emb  = (const float*)d_in[1];
    const float* Wih0 = (const float*)d_in[2];
    const float* Whh0 = (const float*)d_in[3];
    const float* bih0 = (const float*)d_in[4];
    const float* bhh0 = (const float*)d_in[5];
    const float* Wih1 = (const float*)d_in[6];
    const float* Whh1 = (const float*)d_in[7];
    const float* bih1 = (const float*)d_in[8];
    const float* bhh1 = (const float*)d_in[9];
    const float* Wout = (const float*)d_in[10];
    const float* bout = (const float*)d_in[11];
    float* out = (float*)d_out;

    char* p = (char*)d_ws;
    bf16* E    = (bf16*)p;  p += (size_t)T_ * B_ * H_ * 2;      // 32 MB
    bf16* Wp   = (bf16*)p;  p += (size_t)2 * 32 * 65536 * 2;    // 8 MB packed weights
    float* bias0 = (float*)p; p += (size_t)G_ * 4;
    float* bias1 = (float*)p; p += (size_t)G_ * 4;
    char* zbase = p;                                            // zeroed every launch
    bf16* h0ring = (bf16*)p; p += (size_t)8 * B_ * H_ * 2;      // 512 KB
    bf16* h1ring = (bf16*)p; p += (size_t)8 * B_ * H_ * 2;      // 512 KB
    int*  fx     = (int*)p;  p += 8 * 32 * 4;                   // per-strip progress flags
    size_t zbytes = (size_t)(p - zbase);
    float* last1 = (float*)p; p += (size_t)B_ * H_ * 4;
    int* lens = (int*)p; p += 256;

    (void)hipFuncSetAttribute((const void*)k_lstm,
                              hipFuncAttributeMaxDynamicSharedMemorySize, 147456);

    k_zero<<<dim3(128), dim3(256), 0, stream>>>((uint32_t*)zbase, (int)(zbytes / 4));
    k_lens<<<dim3(B_), dim3(256), 0, stream>>>(x, lens);
    k_addb<<<dim3(8), dim3(256), 0, stream>>>(bih0, bhh0, bias0, G_);
    k_addb<<<dim3(8), dim3(256), 0, stream>>>(bih1, bhh1, bias1, G_);
    k_pack<<<dim3(32, 4, 2), dim3(256), 0, stream>>>(Wih0, Whh0, Wih1, Whh1, Wp);
    k_gather<<<dim3(T_, B_), dim3(256), 0, stream>>>(x, emb, E);

    k_lstm<<<dim3(256), dim3(256), 147456, stream>>>(Wp, E, bias0, bias1,
                                                     h0ring, h1ring, fx, last1, lens);

    k_out<<<dim3(B_, TAGS_), dim3(64), 0, stream>>>(last1, Wout, bout, out);
}